// Round 8
// baseline (529.044 us; speedup 1.0000x reference)
//
#include <hip/hip_runtime.h>
#include <hip/hip_bf16.h>
#include <stdint.h>

// GWNN: out = L2(relu(L1(x))),  L(x) = W_wav · diag(f) · W_inv · (x·W)
// R8: big GEMMs (8192x128x8192) with B operand DIRECT global->VGPR (B frags
// are wave-private; LDS round-trip was pure waste). LDS now holds only the
// shared A tile (gload_lds fp32, NBUF=6 ring, 24KB). LDS traffic/step drops
// 72KB -> 20KB, well under the HBM A-drain floor. BM=16, grid 512 -> 2
// independent blocks/CU fill latency bubbles. Exact in-order vmcnt ladder.

typedef __attribute__((ext_vector_type(4))) float f32x4;
typedef __attribute__((ext_vector_type(8))) short s16x8;
typedef __attribute__((ext_vector_type(4))) short s16x4;

#define DEVI static __device__ __forceinline__

DEVI short bf1(float x){ __bf16 h = (__bf16)x; return __builtin_bit_cast(short, h); }

DEVI s16x8 cvt8(f32x4 lo, f32x4 hi){
  s16x8 r;
#pragma unroll
  for (int i = 0; i < 4; ++i){ r[i] = bf1(lo[i]); r[4+i] = bf1(hi[i]); }
  return r;
}

DEVI void glds16(const void* g, void* l){
  __builtin_amdgcn_global_load_lds((const __attribute__((address_space(1))) void*)g,
                                   (__attribute__((address_space(3))) void*)l, 16, 0, 0);
}

template<int N> DEVI void waitvm(){
  if constexpr (N == 0)      asm volatile("s_waitcnt vmcnt(0)" ::: "memory");
  else if constexpr (N == 4) asm volatile("s_waitcnt vmcnt(4)" ::: "memory");
  else if constexpr (N == 5) asm volatile("s_waitcnt vmcnt(5)" ::: "memory");
  else if constexpr (N == 6) asm volatile("s_waitcnt vmcnt(6)" ::: "memory");
}

// ============================================================================
// Big GEMM, B-direct: C[M,128] = A[M,K](f32) @ Bt[128,K](bf16)^T
// BM=16, 4 waves. A: gload_lds ring (6 x 4KB). B: per-wave global->VGPR,
// double-buffered one step ahead. One barrier + one counted vmcnt per step.
// vmcnt ladder (ops: A=1/wave/stage, B=4/wave/step, in-order suffix proof):
//   steady 6; t==0 and t==ns-4 -> 5; t==ns-2,ns-3 -> 4; t==ns-1 -> 0.
// Requires ns = K/64 even and >= 8 (here always 128).
// OUTM: 0 f32 row-major, 1 bf16 row-major, 2 bf16 transposed [128][M].
// ============================================================================
template<bool SCALE, bool RELU, int OUTM>
__global__ __launch_bounds__(256, 2) void gemm_bd(
    const float* __restrict__ Ap, const short* __restrict__ Btp,
    const float* __restrict__ fp, void* __restrict__ Outp, int K, int M)
{
  constexpr int BM = 16, BK = 64;
  constexpr int ASZ = BM*BK*4;     // 4 KB fp32 A tile
  constexpr int NBUF = 6;          // 24 KB LDS
  __shared__ uint8_t lds[NBUF*ASZ];

  const int tid  = threadIdx.x;
  const int lane = tid & 63;
  const int wv   = tid >> 6;
  const int la   = lane & 15;
  const int g4   = lane >> 4;
  const int m0   = blockIdx.x * BM;

  // A staging: wave w stages rows 4w..4w+3; linear LDS dest, XOR-preswizzled src
  const int rA = (wv<<2) + g4;
  const float* gA = Ap + (size_t)(m0+rA)*K + ((la ^ rA)<<2);

  // A fragment read offsets (XOR-swizzled): row la, units v0,v0+1
  int aoff[2][2];
#pragma unroll
  for (int kf = 0; kf < 2; ++kf){
    const int v0 = kf*8 + (g4<<1);
    aoff[kf][0] = la*256 + (((v0  )^la)<<4);
    aoff[kf][1] = la*256 + (((v0+1)^la)<<4);
  }

  // B direct pointers: rows n0 (ni=0) and n0+16 (ni=1); col base g4*8 shorts
  const int n0 = (wv<<5) + la;
  const short* gBn0 = Btp + (size_t)(n0   )*K + (g4<<3);
  const short* gBn1 = Btp + (size_t)(n0+16)*K + (g4<<3);

  f32x4 acc[2] = {};
  s16x8 Be[4], Bo[4];              // [ni*2+kf], named double-buffer (rule #20)

  uint8_t* const lend = lds + NBUF*ASZ;
  uint8_t* bs = lds;               // next stage slot
  uint8_t* bc = lds;               // next compute slot

  auto STAGE = [&](){              // one gload_lds per wave (1 vmcnt op)
    glds16(gA, bs + (wv<<10));
    gA += BK;
    bs += ASZ; if (bs == lend) bs = lds;
  };
  auto LOADB = [&](s16x8* B, int t1){   // 4 plain global loads (4 vmcnt ops)
    const short* p0 = gBn0 + (size_t)t1*BK;
    const short* p1 = gBn1 + (size_t)t1*BK;
    B[0] = *(const s16x8*)(p0);
    B[1] = *(const s16x8*)(p0 + 32);
    B[2] = *(const s16x8*)(p1);
    B[3] = *(const s16x8*)(p1 + 32);
  };
  auto COMPUTE = [&](const s16x8* B){
    const uint8_t* buf = bc;
#pragma unroll
    for (int kf = 0; kf < 2; ++kf){
      s16x8 a = cvt8(*(const f32x4*)(buf + aoff[kf][0]),
                     *(const f32x4*)(buf + aoff[kf][1]));
      acc[0] = __builtin_amdgcn_mfma_f32_16x16x32_bf16(a, B[kf],   acc[0], 0, 0, 0);
      acc[1] = __builtin_amdgcn_mfma_f32_16x16x32_bf16(a, B[2+kf], acc[1], 0, 0, 0);
    }
    bc += ASZ; if (bc == lend) bc = lds;
  };

  const int ns = K >> 6;           // 128 for the big GEMMs

  // prologue: A(0..3), then B(0)
  STAGE(); STAGE(); STAGE(); STAGE();
  LOADB(Be, 0);

  for (int t = 0; t < ns; t += 2){
    // ---- iter t (even): compute with Be
    LOADB(Bo, t+1);                         // B(t+1)
    if (t + 4 < ns) STAGE();                // A(t+4)
    if (t == 0 || t == ns-4) waitvm<5>();
    else if (t == ns-2)      waitvm<4>();
    else                     waitvm<6>();
    __builtin_amdgcn_s_barrier();
    asm volatile("" ::: "memory");
    COMPUTE(Be);
    asm volatile("" ::: "memory");
    // ---- iter t+1 (odd): compute with Bo
    const int u = t + 1;
    if (u + 1 < ns) LOADB(Be, u+1);         // B(t+2)
    if (u + 4 < ns) STAGE();                // A(t+5)
    if (u == ns-3)      waitvm<4>();
    else if (u == ns-1) waitvm<0>();
    else                waitvm<6>();
    __builtin_amdgcn_s_barrier();
    asm volatile("" ::: "memory");
    COMPUTE(Bo);
    asm volatile("" ::: "memory");
  }

  // ---- epilogue
  const int mbase = m0 + (g4<<2);
  const int nc0   = (wv<<5) + la;
  f32x4 fv;
  if constexpr (SCALE) fv = *(const f32x4*)(fp + mbase);
#pragma unroll
  for (int ni = 0; ni < 2; ++ni){
    f32x4 v = acc[ni];
    if constexpr (SCALE) v = v * fv;
    if constexpr (RELU){
#pragma unroll
      for (int r = 0; r < 4; ++r) v[r] = fmaxf(v[r], 0.0f);
    }
    if constexpr (OUTM == 2){
      s16x4 pk;
#pragma unroll
      for (int r = 0; r < 4; ++r) pk[r] = bf1(v[r]);
      *(s16x4*)((short*)Outp + (size_t)(nc0 + (ni<<4))*M + mbase) = pk;
    } else if constexpr (OUTM == 1){
#pragma unroll
      for (int r = 0; r < 4; ++r)
        ((short*)Outp)[(size_t)(mbase + r)*128 + nc0 + (ni<<4)] = bf1(v[r]);
    } else {
#pragma unroll
      for (int r = 0; r < 4; ++r)
        ((float*)Outp)[(size_t)(mbase + r)*128 + nc0 + (ni<<4)] = v[r];
    }
  }
}

// ============================================================================
// Small K=128 GEMM (proven R7 path, B in LDS): out = bf16 transposed [128][M].
// ============================================================================
template<bool ABF>
__global__ __launch_bounds__(256, 1) void gemm_k(
    const void* __restrict__ Ap, const short* __restrict__ Btp,
    void* __restrict__ Outp, int K, int M)
{
  constexpr int BM = 32, BN = 128, BK = 64;
  constexpr int ASZ = ABF ? BM*BK*2 : BM*BK*4;
  constexpr int BSZ = BN*BK*2;
  constexpr int TSZ = ASZ + BSZ;
  constexpr int NL  = ABF ? 5 : 6;
  constexpr int NBUF = 3, PRE = 2;
  __shared__ uint8_t lds[NBUF*TSZ];

  const int tid  = threadIdx.x;
  const int lane = tid & 63;
  const int wv   = tid >> 6;
  const int la   = lane & 15;
  const int g4   = lane >> 4;
  const int m0   = blockIdx.x * BM;

  const float* gA0 = nullptr; const float* gA1 = nullptr; const short* gAh = nullptr;
  if constexpr (!ABF){
    const float* Af = (const float*)Ap;
    int r0 = (wv<<3) + (lane>>4);
    int r1 = r0 + 4;
    gA0 = Af + (size_t)(m0+r0)*K + (((lane&15)^(r0&15))<<2);
    gA1 = Af + (size_t)(m0+r1)*K + (((lane&15)^(r1&15))<<2);
  } else {
    const short* Ah = (const short*)Ap;
    int r = (wv<<3) + (lane>>3);
    gAh = Ah + (size_t)(m0+r)*K + (((lane&7)^(r&7))<<3);
  }
  const int nb0 = (wv<<5) + (lane>>3);
  const short* gB0 = Btp + (size_t)(nb0    )*K + (((lane&7)^(nb0&7))<<3);
  const short* gB1 = Btp + (size_t)(nb0+ 8 )*K + (((lane&7)^(nb0&7))<<3);
  const short* gB2 = Btp + (size_t)(nb0+16 )*K + (((lane&7)^(nb0&7))<<3);
  const short* gB3 = Btp + (size_t)(nb0+24 )*K + (((lane&7)^(nb0&7))<<3);

  int aoff[2][2][2];
  int boff[2][2];
#pragma unroll
  for (int mi = 0; mi < 2; ++mi){
    const int r = mi*16 + la;
#pragma unroll
    for (int kf = 0; kf < 2; ++kf){
      if constexpr (!ABF){
        const int v0 = kf*8 + (g4<<1);
        aoff[mi][kf][0] = r*256 + (((v0  )^(r&15))<<4);
        aoff[mi][kf][1] = r*256 + (((v0+1)^(r&15))<<4);
      } else {
        const int u = kf*4 + g4;
        aoff[mi][kf][0] = r*128 + ((u^(r&7))<<4);
        aoff[mi][kf][1] = 0;
      }
    }
  }
#pragma unroll
  for (int ni = 0; ni < 2; ++ni){
    const int n = (wv<<5) + ni*16 + la;
#pragma unroll
    for (int kf = 0; kf < 2; ++kf){
      const int u = kf*4 + g4;
      boff[ni][kf] = n*128 + ((u^(n&7))<<4);
    }
  }

  f32x4 acc[2][2] = {};

  auto STAGE = [&](uint8_t* buf){
    uint8_t* Ab = buf;
    uint8_t* Bb = buf + ASZ;
    if constexpr (!ABF){
      glds16(gA0, Ab + (wv<<11));
      glds16(gA1, Ab + (wv<<11) + 1024);
      gA0 += BK; gA1 += BK;
    } else {
      glds16(gAh, Ab + (wv<<10));
      gAh += BK;
    }
    glds16(gB0, Bb + (wv<<12));
    glds16(gB1, Bb + (wv<<12) + 1024);
    glds16(gB2, Bb + (wv<<12) + 2048);
    glds16(gB3, Bb + (wv<<12) + 3072);
    gB0 += BK; gB1 += BK; gB2 += BK; gB3 += BK;
  };

  auto COMPUTE = [&](const uint8_t* buf){
    const uint8_t* Ab = buf;
    const uint8_t* Bb = buf + ASZ;
#pragma unroll
    for (int kf = 0; kf < 2; ++kf){
      s16x8 a0, a1, b0, b1;
      if constexpr (!ABF){
        a0 = cvt8(*(const f32x4*)(Ab + aoff[0][kf][0]), *(const f32x4*)(Ab + aoff[0][kf][1]));
        a1 = cvt8(*(const f32x4*)(Ab + aoff[1][kf][0]), *(const f32x4*)(Ab + aoff[1][kf][1]));
      } else {
        a0 = *(const s16x8*)(Ab + aoff[0][kf][0]);
        a1 = *(const s16x8*)(Ab + aoff[1][kf][0]);
      }
      b0 = *(const s16x8*)(Bb + boff[0][kf]);
      b1 = *(const s16x8*)(Bb + boff[1][kf]);
      acc[0][0] = __builtin_amdgcn_mfma_f32_16x16x32_bf16(a0, b0, acc[0][0], 0, 0, 0);
      acc[0][1] = __builtin_amdgcn_mfma_f32_16x16x32_bf16(a0, b1, acc[0][1], 0, 0, 0);
      acc[1][0] = __builtin_amdgcn_mfma_f32_16x16x32_bf16(a1, b0, acc[1][0], 0, 0, 0);
      acc[1][1] = __builtin_amdgcn_mfma_f32_16x16x32_bf16(a1, b1, acc[1][1], 0, 0, 0);
    }
  };

  const int nsteps = K >> 6;
  uint8_t* const lend = lds + NBUF*TSZ;
  uint8_t* bs = lds;
  uint8_t* bc = lds;
  for (int s = 0; s < PRE && s < nsteps; ++s){
    STAGE(bs);
    bs += TSZ; if (bs == lend) bs = lds;
  }
  for (int t = 0; t < nsteps; ++t){
    if (t < nsteps - 1) waitvm<NL>();
    else                waitvm<0>();
    __builtin_amdgcn_s_barrier();
    asm volatile("" ::: "memory");
    if (t + PRE < nsteps){
      STAGE(bs);
      bs += TSZ; if (bs == lend) bs = lds;
    }
    COMPUTE(bc);
    bc += TSZ; if (bc == lend) bc = lds;
    asm volatile("" ::: "memory");
  }

  const int mbase = m0 + (g4<<2);
  const int nc0   = (wv<<5) + la;
#pragma unroll
  for (int mi = 0; mi < 2; ++mi){
#pragma unroll
    for (int ni = 0; ni < 2; ++ni){
      s16x4 pk;
#pragma unroll
      for (int r = 0; r < 4; ++r) pk[r] = bf1(acc[mi][ni][r]);
      *(s16x4*)((short*)Outp + (size_t)(nc0 + (ni<<4))*M + (mbase + (mi<<4))) = pk;
    }
  }
}

// W1T[n][k] = bf16(W1[k][n]), same for W2 — tiny one-shot transpose.
__global__ void wtrans_k(const float* __restrict__ W1, const float* __restrict__ W2,
                         short* __restrict__ T1, short* __restrict__ T2){
  const int idx = blockIdx.x*256 + threadIdx.x;
  const int m = idx >> 14, rem = idx & 16383;
  const int n = rem >> 7, k = rem & 127;
  const float* W = m ? W2 : W1;
  short* T = m ? T2 : T1;
  T[n*128 + k] = bf1(W[k*128 + n]);
}

extern "C" void kernel_launch(void* const* d_in, const int* in_sizes, int n_in,
                              void* d_out, int out_size, void* d_ws, size_t ws_size,
                              hipStream_t stream){
  const float* input = (const float*)d_in[0];
  const float* wav   = (const float*)d_in[1];
  const float* winv  = (const float*)d_in[2];
  const float* W1    = (const float*)d_in[3];
  const float* f1    = (const float*)d_in[4];
  const float* W2    = (const float*)d_in[5];
  const float* f2    = (const float*)d_in[6];

  uint8_t* ws = (uint8_t*)d_ws;
  short* W1T = (short*)(ws);                        // 32 KB
  short* W2T = (short*)(ws + (32<<10));             // 32 KB
  short* XWT = (short*)(ws + (64<<10));             // 2 MB  (x@W transposed bf16)
  short* SPT = (short*)(ws + (64<<10) + (2<<20));   // 2 MB  (filtered spectral, T)
  short* H1  = (short*)(ws + (64<<10) + (4<<20));   // 2 MB  bf16 row-major

  constexpr int M = 8192;
  dim3 b(256);
  dim3 gbd(M/16);        // 512 blocks, 2/CU
  dim3 gns(M/32);        // small K=128 GEMM
  dim3 gt(128);

  wtrans_k<<<gt, b, 0, stream>>>(W1, W2, W1T, W2T);
  // layer 1
  gemm_k<false><<<gns, b, 0, stream>>>(input, W1T, XWT, 128, M);
  gemm_bd<true ,false,2><<<gbd, b, 0, stream>>>(winv, XWT, f1, SPT, M, M);
  gemm_bd<false,true ,1><<<gbd, b, 0, stream>>>(wav,  SPT, nullptr, H1, M, M);
  // layer 2
  gemm_k<true ><<<gns, b, 0, stream>>>(H1, W2T, XWT, 128, M);
  gemm_bd<true ,false,2><<<gbd, b, 0, stream>>>(winv, XWT, f2, SPT, M, M);
  gemm_bd<false,false,0><<<gbd, b, 0, stream>>>(wav,  SPT, nullptr, d_out, M, M);
}

// Round 9
// 361.165 us; speedup vs baseline: 1.4648x; 1.4648x over previous
//
#include <hip/hip_runtime.h>
#include <hip/hip_bf16.h>
#include <stdint.h>

// GWNN: out = L2(relu(L1(x))),  L(x) = W_wav · diag(f) · W_inv · (x·W)
// R9: fused bf16-conversion of the wavelet matrices. Layer-1 big GEMMs read
// fp32 A (as before) and wave 0 streams out the cvt'd bf16 A tile (winv16 /
// wav16, 128MB each in ws). Layer-2 big GEMMs read the bf16 copies via the
// proven ABF=1 path -> half the HBM bytes. Counted-vmcnt ladders stay exact:
// wave 0 (issues 4 extra stores/step) uses 6/10/14/0; waves 1-3 keep 6/0.
// Falls back to the R5 all-fp32 plan if ws_size can't hold the copies.

typedef __attribute__((ext_vector_type(4))) float f32x4;
typedef __attribute__((ext_vector_type(8))) short s16x8;
typedef __attribute__((ext_vector_type(4))) short s16x4;

#define DEVI static __device__ __forceinline__

DEVI short bf1(float x){ __bf16 h = (__bf16)x; return __builtin_bit_cast(short, h); }

DEVI s16x8 cvt8(f32x4 lo, f32x4 hi){
  s16x8 r;
#pragma unroll
  for (int i = 0; i < 4; ++i){ r[i] = bf1(lo[i]); r[4+i] = bf1(hi[i]); }
  return r;
}

DEVI void glds16(const void* g, void* l){
  __builtin_amdgcn_global_load_lds((const __attribute__((address_space(1))) void*)g,
                                   (__attribute__((address_space(3))) void*)l, 16, 0, 0);
}

template<int N> DEVI void waitvm(){
  if constexpr (N == 0)       asm volatile("s_waitcnt vmcnt(0)"  ::: "memory");
  else if constexpr (N == 5)  asm volatile("s_waitcnt vmcnt(5)"  ::: "memory");
  else if constexpr (N == 6)  asm volatile("s_waitcnt vmcnt(6)"  ::: "memory");
  else if constexpr (N == 10) asm volatile("s_waitcnt vmcnt(10)" ::: "memory");
  else if constexpr (N == 14) asm volatile("s_waitcnt vmcnt(14)" ::: "memory");
}

// ============================================================================
// Big GEMM (M x 128 x K): C = A @ Bt^T.
// A fp32 (ABF=0, cvt->bf16 at LDS read; optional WCOPY: wave 0 streams the
// cvt'd bf16 A to Acp) or bf16 (ABF=1). Bt bf16 row-major [128][K].
// OUTM: 0 f32 row-major, 1 bf16 row-major, 2 bf16 transposed [128][M].
// SCALE: row scale by fp[m]. RELU on store. BM=32, NBUF=3 ring, PRE=2,
// one barrier + exact counted vmcnt per K-step.
// ============================================================================
template<bool ABF, bool WCOPY, bool SCALE, bool RELU, int OUTM>
__global__ __launch_bounds__(256, 1) void ggemm(
    const void* __restrict__ Ap, const short* __restrict__ Btp,
    const float* __restrict__ fp, void* __restrict__ Outp,
    short* __restrict__ Acp, int K, int M)
{
  constexpr int BM = 32, BN = 128, BK = 64;
  constexpr int ASZ = ABF ? BM*BK*2 : BM*BK*4;
  constexpr int BSZ = BN*BK*2;
  constexpr int TSZ = ASZ + BSZ;
  constexpr int NL  = ABF ? 5 : 6;
  constexpr int NBUF = 3, PRE = 2;
  __shared__ uint8_t lds[NBUF*TSZ];

  const int tid  = threadIdx.x;
  const int lane = tid & 63;
  const int wv   = tid >> 6;
  const int la   = lane & 15;
  const int g4   = lane >> 4;
  const int m0   = blockIdx.x * BM;
  const bool w0u = (__builtin_amdgcn_readfirstlane(wv) == 0);

  // ---- staging pointers (global source pre-swizzled; LDS dest linear)
  const float* gA0 = nullptr; const float* gA1 = nullptr; const short* gAh = nullptr;
  if constexpr (!ABF){
    const float* Af = (const float*)Ap;
    int r0 = (wv<<3) + (lane>>4);
    int r1 = r0 + 4;
    gA0 = Af + (size_t)(m0+r0)*K + (((lane&15)^(r0&15))<<2);
    gA1 = Af + (size_t)(m0+r1)*K + (((lane&15)^(r1&15))<<2);
  } else {
    const short* Ah = (const short*)Ap;
    int r = (wv<<3) + (lane>>3);
    gAh = Ah + (size_t)(m0+r)*K + (((lane&7)^(r&7))<<3);
  }
  const int nb0 = (wv<<5) + (lane>>3);
  const short* gB0 = Btp + (size_t)(nb0    )*K + (((lane&7)^(nb0&7))<<3);
  const short* gB1 = Btp + (size_t)(nb0+ 8 )*K + (((lane&7)^(nb0&7))<<3);
  const short* gB2 = Btp + (size_t)(nb0+16 )*K + (((lane&7)^(nb0&7))<<3);
  const short* gB3 = Btp + (size_t)(nb0+24 )*K + (((lane&7)^(nb0&7))<<3);

  // ---- bf16 A-copy stream pointers (wave 0 only writes; ptr arith uniform)
  short* wc0 = nullptr; short* wc1 = nullptr;
  if constexpr (WCOPY){
    wc0 = Acp + (size_t)(m0 + la)*K + (g4<<3);
    wc1 = wc0 + (size_t)16*K;
  }

  // ---- fragment LDS byte offsets (XOR-swizzled reads)
  int aoff[2][2][2];
  int boff[2][2];
#pragma unroll
  for (int mi = 0; mi < 2; ++mi){
    const int r = mi*16 + la;
#pragma unroll
    for (int kf = 0; kf < 2; ++kf){
      if constexpr (!ABF){
        const int v0 = kf*8 + (g4<<1);
        aoff[mi][kf][0] = r*256 + (((v0  )^(r&15))<<4);
        aoff[mi][kf][1] = r*256 + (((v0+1)^(r&15))<<4);
      } else {
        const int u = kf*4 + g4;
        aoff[mi][kf][0] = r*128 + ((u^(r&7))<<4);
        aoff[mi][kf][1] = 0;
      }
    }
  }
#pragma unroll
  for (int ni = 0; ni < 2; ++ni){
    const int n = (wv<<5) + ni*16 + la;
#pragma unroll
    for (int kf = 0; kf < 2; ++kf){
      const int u = kf*4 + g4;
      boff[ni][kf] = n*128 + ((u^(n&7))<<4);
    }
  }

  f32x4 acc[2][2] = {};

  auto STAGE = [&](uint8_t* buf){
    uint8_t* Ab = buf;
    uint8_t* Bb = buf + ASZ;
    if constexpr (!ABF){
      glds16(gA0, Ab + (wv<<11));
      glds16(gA1, Ab + (wv<<11) + 1024);
      gA0 += BK; gA1 += BK;
    } else {
      glds16(gAh, Ab + (wv<<10));
      gAh += BK;
    }
    glds16(gB0, Bb + (wv<<12));
    glds16(gB1, Bb + (wv<<12) + 1024);
    glds16(gB2, Bb + (wv<<12) + 2048);
    glds16(gB3, Bb + (wv<<12) + 3072);
    gB0 += BK; gB1 += BK; gB2 += BK; gB3 += BK;
  };

  auto COMPUTE = [&](const uint8_t* buf){
    const uint8_t* Ab = buf;
    const uint8_t* Bb = buf + ASZ;
#pragma unroll
    for (int kf = 0; kf < 2; ++kf){
      s16x8 a0, a1, b0, b1;
      if constexpr (!ABF){
        a0 = cvt8(*(const f32x4*)(Ab + aoff[0][kf][0]), *(const f32x4*)(Ab + aoff[0][kf][1]));
        a1 = cvt8(*(const f32x4*)(Ab + aoff[1][kf][0]), *(const f32x4*)(Ab + aoff[1][kf][1]));
        if constexpr (WCOPY){
          if (w0u){                              // scalar-branch: only wave 0's
            *(s16x8*)(wc0 + kf*32) = a0;         // vmcnt stream gains 4 stores
            *(s16x8*)(wc1 + kf*32) = a1;
          }
        }
      } else {
        a0 = *(const s16x8*)(Ab + aoff[0][kf][0]);
        a1 = *(const s16x8*)(Ab + aoff[1][kf][0]);
      }
      b0 = *(const s16x8*)(Bb + boff[0][kf]);
      b1 = *(const s16x8*)(Bb + boff[1][kf]);
      acc[0][0] = __builtin_amdgcn_mfma_f32_16x16x32_bf16(a0, b0, acc[0][0], 0, 0, 0);
      acc[0][1] = __builtin_amdgcn_mfma_f32_16x16x32_bf16(a0, b1, acc[0][1], 0, 0, 0);
      acc[1][0] = __builtin_amdgcn_mfma_f32_16x16x32_bf16(a1, b0, acc[1][0], 0, 0, 0);
      acc[1][1] = __builtin_amdgcn_mfma_f32_16x16x32_bf16(a1, b1, acc[1][1], 0, 0, 0);
    }
    if constexpr (WCOPY){ wc0 += BK; wc1 += BK; }
  };

  const int ns = K >> 6;
  uint8_t* const lend = lds + NBUF*TSZ;
  uint8_t* bs = lds;
  uint8_t* bc = lds;
  for (int s = 0; s < PRE && s < ns; ++s){
    STAGE(bs);
    bs += TSZ; if (bs == lend) bs = lds;
  }
  for (int t = 0; t < ns; ++t){
    // exact per-wave counted-vmcnt ladder
    if constexpr (WCOPY){
      if (w0u){            // wave 0 stream: 6 loads + 4 stores per iter
        if (t == 0)           waitvm<6>();
        else if (t == 1)      waitvm<10>();
        else if (t <= ns - 2) waitvm<14>();
        else                  waitvm<0>();
      } else {
        if (t < ns - 1) waitvm<6>(); else waitvm<0>();
      }
    } else {
      if (t < ns - 1) waitvm<NL>(); else waitvm<0>();
    }
    __builtin_amdgcn_s_barrier();
    asm volatile("" ::: "memory");
    if (t + PRE < ns){
      STAGE(bs);
      bs += TSZ; if (bs == lend) bs = lds;
    }
    COMPUTE(bc);
    bc += TSZ; if (bc == lend) bc = lds;
    asm volatile("" ::: "memory");
  }

  // ---- epilogue
  const int mbase = m0 + (g4<<2);
  const int nc0   = (wv<<5) + la;
  f32x4 fv0, fv1;
  if constexpr (SCALE){
    fv0 = *(const f32x4*)(fp + mbase);
    fv1 = *(const f32x4*)(fp + mbase + 16);
  }
#pragma unroll
  for (int mi = 0; mi < 2; ++mi){
#pragma unroll
    for (int ni = 0; ni < 2; ++ni){
      f32x4 v = acc[mi][ni];
      if constexpr (SCALE) v = v * (mi ? fv1 : fv0);
      if constexpr (RELU){
#pragma unroll
        for (int r = 0; r < 4; ++r) v[r] = fmaxf(v[r], 0.0f);
      }
      if constexpr (OUTM == 2){
        s16x4 pk;
#pragma unroll
        for (int r = 0; r < 4; ++r) pk[r] = bf1(v[r]);
        *(s16x4*)((short*)Outp + (size_t)(nc0 + (ni<<4))*M + (mbase + (mi<<4))) = pk;
      } else if constexpr (OUTM == 1){
#pragma unroll
        for (int r = 0; r < 4; ++r)
          ((short*)Outp)[(size_t)(mbase + (mi<<4) + r)*BN + nc0 + (ni<<4)] = bf1(v[r]);
      } else {
#pragma unroll
        for (int r = 0; r < 4; ++r)
          ((float*)Outp)[(size_t)(mbase + (mi<<4) + r)*BN + nc0 + (ni<<4)] = v[r];
      }
    }
  }
}

// ============================================================================
// Small K=128 GEMM (proven path): out = bf16 transposed [128][M].
// ============================================================================
template<bool ABF>
__global__ __launch_bounds__(256, 1) void sgemm(
    const void* __restrict__ Ap, const short* __restrict__ Btp,
    void* __restrict__ Outp, int K, int M)
{
  constexpr int BM = 32, BN = 128, BK = 64;
  constexpr int ASZ = ABF ? BM*BK*2 : BM*BK*4;
  constexpr int BSZ = BN*BK*2;
  constexpr int TSZ = ASZ + BSZ;
  constexpr int NL  = ABF ? 5 : 6;
  constexpr int NBUF = 3, PRE = 2;
  __shared__ uint8_t lds[NBUF*TSZ];

  const int tid  = threadIdx.x;
  const int lane = tid & 63;
  const int wv   = tid >> 6;
  const int la   = lane & 15;
  const int g4   = lane >> 4;
  const int m0   = blockIdx.x * BM;

  const float* gA0 = nullptr; const float* gA1 = nullptr; const short* gAh = nullptr;
  if constexpr (!ABF){
    const float* Af = (const float*)Ap;
    int r0 = (wv<<3) + (lane>>4);
    int r1 = r0 + 4;
    gA0 = Af + (size_t)(m0+r0)*K + (((lane&15)^(r0&15))<<2);
    gA1 = Af + (size_t)(m0+r1)*K + (((lane&15)^(r1&15))<<2);
  } else {
    const short* Ah = (const short*)Ap;
    int r = (wv<<3) + (lane>>3);
    gAh = Ah + (size_t)(m0+r)*K + (((lane&7)^(r&7))<<3);
  }
  const int nb0 = (wv<<5) + (lane>>3);
  const short* gB0 = Btp + (size_t)(nb0    )*K + (((lane&7)^(nb0&7))<<3);
  const short* gB1 = Btp + (size_t)(nb0+ 8 )*K + (((lane&7)^(nb0&7))<<3);
  const short* gB2 = Btp + (size_t)(nb0+16 )*K + (((lane&7)^(nb0&7))<<3);
  const short* gB3 = Btp + (size_t)(nb0+24 )*K + (((lane&7)^(nb0&7))<<3);

  int aoff[2][2][2];
  int boff[2][2];
#pragma unroll
  for (int mi = 0; mi < 2; ++mi){
    const int r = mi*16 + la;
#pragma unroll
    for (int kf = 0; kf < 2; ++kf){
      if constexpr (!ABF){
        const int v0 = kf*8 + (g4<<1);
        aoff[mi][kf][0] = r*256 + (((v0  )^(r&15))<<4);
        aoff[mi][kf][1] = r*256 + (((v0+1)^(r&15))<<4);
      } else {
        const int u = kf*4 + g4;
        aoff[mi][kf][0] = r*128 + ((u^(r&7))<<4);
        aoff[mi][kf][1] = 0;
      }
    }
  }
#pragma unroll
  for (int ni = 0; ni < 2; ++ni){
    const int n = (wv<<5) + ni*16 + la;
#pragma unroll
    for (int kf = 0; kf < 2; ++kf){
      const int u = kf*4 + g4;
      boff[ni][kf] = n*128 + ((u^(n&7))<<4);
    }
  }

  f32x4 acc[2][2] = {};

  auto STAGE = [&](uint8_t* buf){
    uint8_t* Ab = buf;
    uint8_t* Bb = buf + ASZ;
    if constexpr (!ABF){
      glds16(gA0, Ab + (wv<<11));
      glds16(gA1, Ab + (wv<<11) + 1024);
      gA0 += BK; gA1 += BK;
    } else {
      glds16(gAh, Ab + (wv<<10));
      gAh += BK;
    }
    glds16(gB0, Bb + (wv<<12));
    glds16(gB1, Bb + (wv<<12) + 1024);
    glds16(gB2, Bb + (wv<<12) + 2048);
    glds16(gB3, Bb + (wv<<12) + 3072);
    gB0 += BK; gB1 += BK; gB2 += BK; gB3 += BK;
  };

  auto COMPUTE = [&](const uint8_t* buf){
    const uint8_t* Ab = buf;
    const uint8_t* Bb = buf + ASZ;
#pragma unroll
    for (int kf = 0; kf < 2; ++kf){
      s16x8 a0, a1, b0, b1;
      if constexpr (!ABF){
        a0 = cvt8(*(const f32x4*)(Ab + aoff[0][kf][0]), *(const f32x4*)(Ab + aoff[0][kf][1]));
        a1 = cvt8(*(const f32x4*)(Ab + aoff[1][kf][0]), *(const f32x4*)(Ab + aoff[1][kf][1]));
      } else {
        a0 = *(const s16x8*)(Ab + aoff[0][kf][0]);
        a1 = *(const s16x8*)(Ab + aoff[1][kf][0]);
      }
      b0 = *(const s16x8*)(Bb + boff[0][kf]);
      b1 = *(const s16x8*)(Bb + boff[1][kf]);
      acc[0][0] = __builtin_amdgcn_mfma_f32_16x16x32_bf16(a0, b0, acc[0][0], 0, 0, 0);
      acc[0][1] = __builtin_amdgcn_mfma_f32_16x16x32_bf16(a0, b1, acc[0][1], 0, 0, 0);
      acc[1][0] = __builtin_amdgcn_mfma_f32_16x16x32_bf16(a1, b0, acc[1][0], 0, 0, 0);
      acc[1][1] = __builtin_amdgcn_mfma_f32_16x16x32_bf16(a1, b1, acc[1][1], 0, 0, 0);
    }
  };

  const int ns = K >> 6;
  uint8_t* const lend = lds + NBUF*TSZ;
  uint8_t* bs = lds;
  uint8_t* bc = lds;
  for (int s = 0; s < PRE && s < ns; ++s){
    STAGE(bs);
    bs += TSZ; if (bs == lend) bs = lds;
  }
  for (int t = 0; t < ns; ++t){
    if (t < ns - 1) waitvm<NL>(); else waitvm<0>();
    __builtin_amdgcn_s_barrier();
    asm volatile("" ::: "memory");
    if (t + PRE < ns){
      STAGE(bs);
      bs += TSZ; if (bs == lend) bs = lds;
    }
    COMPUTE(bc);
    bc += TSZ; if (bc == lend) bc = lds;
    asm volatile("" ::: "memory");
  }

  const int mbase = m0 + (g4<<2);
  const int nc0   = (wv<<5) + la;
#pragma unroll
  for (int mi = 0; mi < 2; ++mi){
#pragma unroll
    for (int ni = 0; ni < 2; ++ni){
      s16x4 pk;
#pragma unroll
      for (int r = 0; r < 4; ++r) pk[r] = bf1(acc[mi][ni][r]);
      *(s16x4*)((short*)Outp + (size_t)(nc0 + (ni<<4))*M + (mbase + (mi<<4))) = pk;
    }
  }
}

// W1T[n][k] = bf16(W1[k][n]), same for W2 — tiny one-shot transpose.
__global__ void wtrans_k(const float* __restrict__ W1, const float* __restrict__ W2,
                         short* __restrict__ T1, short* __restrict__ T2){
  const int idx = blockIdx.x*256 + threadIdx.x;
  const int m = idx >> 14, rem = idx & 16383;
  const int n = rem >> 7, k = rem & 127;
  const float* W = m ? W2 : W1;
  short* T = m ? T2 : T1;
  T[n*128 + k] = bf1(W[k*128 + n]);
}

extern "C" void kernel_launch(void* const* d_in, const int* in_sizes, int n_in,
                              void* d_out, int out_size, void* d_ws, size_t ws_size,
                              hipStream_t stream){
  const float* input = (const float*)d_in[0];
  const float* wav   = (const float*)d_in[1];
  const float* winv  = (const float*)d_in[2];
  const float* W1    = (const float*)d_in[3];
  const float* f1    = (const float*)d_in[4];
  const float* W2    = (const float*)d_in[5];
  const float* f2    = (const float*)d_in[6];

  constexpr int M = 8192;
  uint8_t* ws = (uint8_t*)d_ws;
  short* W1T = (short*)(ws);                          // 32 KB
  short* W2T = (short*)(ws + (32<<10));               // 32 KB
  short* XWT = (short*)(ws + (64<<10));               // 2 MB
  short* SPT = (short*)(ws + (64<<10) + (2<<20));     // 2 MB
  short* H1  = (short*)(ws + (64<<10) + (4<<20));     // 2 MB
  short* WI16 = (short*)(ws + (64<<10) + (6<<20));            // 128 MB winv bf16
  short* WA16 = WI16 + (size_t)M*M;                            // 128 MB wav  bf16
  const size_t needed = (64<<10) + (size_t)(6<<20) + 2*(size_t)M*M*2;
  const bool big = (ws_size >= needed);

  dim3 b(256), g(M/32), gt(128);

  wtrans_k<<<gt, b, 0, stream>>>(W1, W2, W1T, W2T);
  sgemm<false><<<g, b, 0, stream>>>(input, W1T, XWT, 128, M);
  if (big){
    // layer 1: fp32 A + fused bf16-copy stream
    ggemm<false,true ,true ,false,2><<<g,b,0,stream>>>(winv, XWT, f1, SPT, WI16, M, M);
    ggemm<false,true ,false,true ,1><<<g,b,0,stream>>>(wav,  SPT, nullptr, H1, WA16, M, M);
    sgemm<true ><<<g, b, 0, stream>>>(H1, W2T, XWT, 128, M);
    // layer 2: bf16 A (half the HBM bytes)
    ggemm<true ,false,true ,false,2><<<g,b,0,stream>>>(WI16, XWT, f2, SPT, nullptr, M, M);
    ggemm<true ,false,false,false,0><<<g,b,0,stream>>>(WA16, SPT, nullptr, d_out, nullptr, M, M);
  } else {
    // fallback: all-fp32 A (R5 behavior)
    ggemm<false,false,true ,false,2><<<g,b,0,stream>>>(winv, XWT, f1, SPT, nullptr, M, M);
    ggemm<false,false,false,true ,1><<<g,b,0,stream>>>(wav,  SPT, nullptr, H1, nullptr, M, M);
    sgemm<true ><<<g, b, 0, stream>>>(H1, W2T, XWT, 128, M);
    ggemm<false,false,true ,false,2><<<g,b,0,stream>>>(winv, XWT, f2, SPT, nullptr, M, M);
    ggemm<false,false,false,false,0><<<g,b,0,stream>>>(wav,  SPT, nullptr, d_out, nullptr, M, M);
  }
}